// Round 3
// baseline (154.665 us; speedup 1.0000x reference)
//
#include <hip/hip_runtime.h>

#define BATCH 4
#define NDIM 2048
#define MDIM 2048
#define CDIM 128

typedef short bf16x8 __attribute__((ext_vector_type(8)));   // 8 bf16 (4 VGPRs)
typedef float f32x4  __attribute__((ext_vector_type(4)));   // MFMA accumulator

// fp32 -> bf16 bits, round-to-nearest-even (inputs are finite normals).
__device__ __forceinline__ unsigned short f2bf(float f) {
    union { float f; unsigned int u; } v; v.f = f;
    unsigned int u = v.u;
    return (unsigned short)((u + 0x7FFFu + ((u >> 16) & 1u)) >> 16);
}

// Kernel 1: per-row squared norms in fp32.
// ws[0..8191]     = ssq for src rows (b*2048+n)
// ws[8192..16383] = tsq for tgt rows
__global__ __launch_bounds__(256) void norm_kernel(
    const float* __restrict__ src, const float* __restrict__ tgt,
    float* __restrict__ ws)
{
    int gid  = blockIdx.x * 256 + threadIdx.x;
    int wid  = gid >> 6;          // one wave per row, 16384 waves
    int lane = gid & 63;
    const float* base = (wid < BATCH * NDIM)
        ? (src + (size_t)wid * CDIM)
        : (tgt + (size_t)(wid - BATCH * NDIM) * CDIM);
    float2 v = ((const float2*)base)[lane];
    float s = v.x * v.x + v.y * v.y;
    #pragma unroll
    for (int off = 32; off >= 1; off >>= 1) s += __shfl_xor(s, off, 64);
    if (lane == 0) ws[wid] = s;
}

// Kernel 2: 128x128 output tile per block; bf16 MFMA dots, fused epilogue.
// K=128 staged in two single-buffered K=64 halves -> LDS = 32 KiB total ->
// 4 blocks/CU (launch_bounds(256,4) caps VGPR at 128 = 4 waves/SIMD).
// Rows are 64 bf16 = 8x16B chunks, XOR-swizzled (c ^ (row&7)): staging
// writes and MFMA fragment reads are both <=2-way (free).
__global__ __launch_bounds__(256, 4) void sim_mfma(
    const float* __restrict__ src, const float* __restrict__ tgt,
    const float* __restrict__ ws, float* __restrict__ out)
{
    __shared__ unsigned short As[128 * 64];   // src K-half tile, bf16 bits
    __shared__ unsigned short Bs[128 * 64];   // tgt K-half tile, bf16 bits

    const int tid = threadIdx.x;
    const int b   = blockIdx.z;
    const int i0  = blockIdx.y << 7;   // src-row base of tile
    const int j0  = blockIdx.x << 7;   // tgt-row base of tile

    const float4* s4 = (const float4*)(src + ((size_t)b * NDIM + i0) * CDIM);
    const float4* t4 = (const float4*)(tgt + ((size_t)b * MDIM + j0) * CDIM);

    const int wave = tid >> 6;
    const int lane = tid & 63;
    const int wm   = (wave & 1) << 6;   // 64x64 quadrant per wave
    const int wn   = (wave >> 1) << 6;
    const int l16  = lane & 15;
    const int q    = lane >> 4;

    f32x4 acc[4][4];
    #pragma unroll
    for (int i = 0; i < 4; ++i)
        #pragma unroll
        for (int j = 0; j < 4; ++j) acc[i][j] = (f32x4){0.f, 0.f, 0.f, 0.f};

    #pragma unroll
    for (int h = 0; h < 2; ++h) {
        if (h) __syncthreads();   // all frag reads of half 0 done before overwrite

        // Stage K-half h: 128 rows x 64 floats -> bf16. 2048 float4/tensor,
        // 8 per thread. Consecutive lanes -> consecutive float4 (coalesced).
        #pragma unroll 2
        for (int it = 0; it < 8; ++it) {
            int idx = tid + it * 256;      // 0..2047
            int row = idx >> 4;            // 0..127
            int c4  = idx & 15;            // float4 within K-half
            float4 va = s4[row * 32 + h * 16 + c4];
            float4 vb = t4[row * 32 + h * 16 + c4];
            int c   = c4 >> 1;             // 16B chunk 0..7
            int hf  = c4 & 1;
            int off = row * 64 + (((c ^ (row & 7)) << 3) + (hf << 2));
            ushort4 ua, ub;
            ua.x = f2bf(va.x); ua.y = f2bf(va.y); ua.z = f2bf(va.z); ua.w = f2bf(va.w);
            ub.x = f2bf(vb.x); ub.y = f2bf(vb.y); ub.z = f2bf(vb.z); ub.w = f2bf(vb.w);
            *(ushort4*)&As[off] = ua;
            *(ushort4*)&Bs[off] = ub;
        }
        __syncthreads();

        // 2 MFMA k-steps of 32 per half. chunk = k0*4+q in 0..7;
        // row&7 == l16&7 for all frag rows -> swizzle = c ^ (l16&7).
        #pragma unroll
        for (int k0 = 0; k0 < 2; ++k0) {
            int c   = (k0 << 2) + q;
            int swz = (c ^ (l16 & 7)) << 3;
            bf16x8 a[4], bv[4];
            #pragma unroll
            for (int i = 0; i < 4; ++i)
                a[i] = *(const bf16x8*)&As[(wm + (i << 4) + l16) * 64 + swz];
            #pragma unroll
            for (int j = 0; j < 4; ++j)
                bv[j] = *(const bf16x8*)&Bs[(wn + (j << 4) + l16) * 64 + swz];
            #pragma unroll
            for (int i = 0; i < 4; ++i)
                #pragma unroll
                for (int j = 0; j < 4; ++j)
                    acc[i][j] = __builtin_amdgcn_mfma_f32_16x16x32_bf16(
                        a[i], bv[j], acc[i][j], 0, 0, 0);
        }
    }

    // Epilogue. D layout: col(n-dim of D = tgt idx) = lane&15, row = q*4+reg.
    const float* nrmS = ws + (size_t)b * NDIM + i0;
    const float* nrmT = ws + (size_t)BATCH * NDIM + (size_t)b * MDIM + j0;

    float sq[4][4], isq[4][4];
    #pragma unroll
    for (int i = 0; i < 4; ++i) {
        float4 s4v = *(const float4*)&nrmS[wm + (i << 4) + (q << 2)];
        sq[i][0] = s4v.x; sq[i][1] = s4v.y; sq[i][2] = s4v.z; sq[i][3] = s4v.w;
        #pragma unroll
        for (int r = 0; r < 4; ++r)
            isq[i][r] = __builtin_amdgcn_rsqf(fmaxf(sq[i][r], 1e-24f));
    }
    float tq[4], itq[4];
    #pragma unroll
    for (int j = 0; j < 4; ++j) {
        tq[j]  = nrmT[wn + (j << 4) + l16];
        itq[j] = __builtin_amdgcn_rsqf(fmaxf(tq[j], 1e-24f));
    }

    float2* out2 = (float2*)out;
    #pragma unroll
    for (int i = 0; i < 4; ++i) {
        #pragma unroll
        for (int r = 0; r < 4; ++r) {
            int mrow = wm + (i << 4) + (q << 2) + r;          // src idx in tile
            size_t rowbase = ((size_t)b * NDIM + (size_t)(i0 + mrow)) * MDIM + j0;
            float sqr = sq[i][r], isr = isq[i][r];
            #pragma unroll
            for (int j = 0; j < 4; ++j) {
                int ncol = wn + (j << 4) + l16;               // tgt idx in tile
                float d   = acc[i][j][r];
                float cs  = d * isr * itq[j];
                float dsq = fmaf(-2.0f, d, sqr + tq[j]);
                float fd  = __builtin_amdgcn_sqrtf(fmaxf(dsq, 0.0f));
                float fdn = __builtin_amdgcn_rcpf(1.0f + fd);
                out2[rowbase + ncol] = make_float2(cs, fdn);
            }
        }
    }
}

extern "C" void kernel_launch(void* const* d_in, const int* in_sizes, int n_in,
                              void* d_out, int out_size, void* d_ws, size_t ws_size,
                              hipStream_t stream) {
    const float* src = (const float*)d_in[0];
    const float* tgt = (const float*)d_in[1];
    float* ws  = (float*)d_ws;
    float* out = (float*)d_out;

    // 16384 rows, one wave each -> 4096 blocks of 256.
    norm_kernel<<<dim3(4096), dim3(256), 0, stream>>>(src, tgt, ws);

    dim3 grid(MDIM / 128, NDIM / 128, BATCH);
    sim_mfma<<<grid, dim3(256), 0, stream>>>(src, tgt, ws, out);
}

// Round 4
// 151.132 us; speedup vs baseline: 1.0234x; 1.0234x over previous
//
#include <hip/hip_runtime.h>

#define BATCH 4
#define NDIM 2048
#define MDIM 2048
#define CDIM 128

typedef short bf16x8 __attribute__((ext_vector_type(8)));   // 8 bf16 (4 VGPRs)
typedef float f32x4  __attribute__((ext_vector_type(4)));   // MFMA accumulator
typedef float f32x2  __attribute__((ext_vector_type(2)));

// ws layout (floats): [0..8191] ssq, [8192..16383] tsq,
// then bf16 image: src rows 0..8191, tgt rows 8192..16383 (128 bf16/row),
// each row's 16-byte chunks stored XOR-swizzled: chunk c at position c^(row&15).
#define WS_BF16_OFF 16384   // in floats

// pack two fp32 -> two bf16 (RNE), little-endian (lo -> short 0).
__device__ __forceinline__ unsigned int pack2bf(float lo, float hi) {
    union { float f; unsigned int u; } a, b;
    a.f = lo; b.f = hi;
    unsigned int ua = (a.u + 0x7FFFu + ((a.u >> 16) & 1u)) >> 16;
    unsigned int ub = (b.u + 0x7FFFu + ((b.u >> 16) & 1u)) & 0xFFFF0000u;
    return ua | ub;
}

// Kernel 1: per-row fp32 squared norms + bf16 conversion, swizzle-packed.
// One wave per row (16384 rows); lane holds floats {2*lane, 2*lane+1}.
__global__ __launch_bounds__(256) void prep_kernel(
    const float* __restrict__ src, const float* __restrict__ tgt,
    float* __restrict__ ws)
{
    int gid  = blockIdx.x * 256 + threadIdx.x;
    int wid  = gid >> 6;          // global row id 0..16383 (src then tgt)
    int lane = gid & 63;
    const float* base = (wid < BATCH * NDIM)
        ? (src + (size_t)wid * CDIM)
        : (tgt + (size_t)(wid - BATCH * NDIM) * CDIM);
    float2 v = ((const float2*)base)[lane];

    // bf16 write: chunk c = lane>>2 (4 lanes per 16B chunk), swizzled pos.
    unsigned short* wsbf = (unsigned short*)(ws + WS_BF16_OFF);
    int pos = ((lane >> 2) ^ (wid & 15));
    *(unsigned int*)&wsbf[(size_t)wid * 128 + pos * 8 + (lane & 3) * 2] =
        pack2bf(v.x, v.y);

    float s = v.x * v.x + v.y * v.y;
    #pragma unroll
    for (int off = 32; off >= 1; off >>= 1) s += __shfl_xor(s, off, 64);
    if (lane == 0) ws[wid] = s;
}

// Kernel 2: 128x128 output tile per block. Staging = pure identity DMA
// (global_load_lds dwordx4) from the pre-swizzled bf16 image -> zero staging
// VALU, zero ds_writes, one barrier. Full K=128 resident (64 KiB LDS,
// 2 blocks/CU). Fused epilogue with non-temporal float2 stores.
__global__ __launch_bounds__(256) void sim_mfma(
    const float* __restrict__ ws, float* __restrict__ out)
{
    __shared__ unsigned short As[128 * 128];   // swizzled bf16 src tile
    __shared__ unsigned short Bs[128 * 128];   // swizzled bf16 tgt tile

    const int tid = threadIdx.x;
    const int b   = blockIdx.z;
    const int i0  = blockIdx.y << 7;
    const int j0  = blockIdx.x << 7;

    const unsigned short* wsbf = (const unsigned short*)(ws + WS_BF16_OFF);
    const unsigned short* gA = wsbf + ((size_t)b * NDIM + i0) * 128;
    const unsigned short* gB = wsbf + ((size_t)(BATCH * NDIM) + (size_t)b * MDIM + j0) * 128;

    const int wave = tid >> 6;
    const int lane = tid & 63;

    // Each wave DMAs 8 KiB of A and 8 KiB of B: 16-B slot s -> LDS byte s*16.
    // Wave-uniform LDS base + lane*16 (HW rule) == slot (base+lane) exactly.
    {
        int slot0 = wave * 512;
        #pragma unroll
        for (int k = 0; k < 8; ++k) {
            int s = slot0 + k * 64;
            __builtin_amdgcn_global_load_lds(
                (const __attribute__((address_space(1))) void*)(gA + (size_t)(s + lane) * 8),
                (__attribute__((address_space(3))) void*)&As[s * 8], 16, 0, 0);
            __builtin_amdgcn_global_load_lds(
                (const __attribute__((address_space(1))) void*)(gB + (size_t)(s + lane) * 8),
                (__attribute__((address_space(3))) void*)&Bs[s * 8], 16, 0, 0);
        }
    }
    __syncthreads();   // compiler drains vmcnt(0) before s_barrier

    const int wm  = (wave & 1) << 6;   // 64x64 quadrant per wave
    const int wn  = (wave >> 1) << 6;
    const int l16 = lane & 15;
    const int q   = lane >> 4;

    f32x4 acc[4][4];
    #pragma unroll
    for (int i = 0; i < 4; ++i)
        #pragma unroll
        for (int j = 0; j < 4; ++j) acc[i][j] = (f32x4){0.f, 0.f, 0.f, 0.f};

    // K=128 in 4 MFMA k-steps of 32. Fragment row%16 == l16, so the
    // swizzled chunk position is (k0*4+q) ^ l16 (same mapping that the
    // prep kernel wrote). Bank load is even (2x per quarter-wave).
    #pragma unroll
    for (int k0 = 0; k0 < 4; ++k0) {
        int chunk = (k0 << 2) + q;
        int swz   = (chunk ^ l16) << 3;
        bf16x8 a[4], bv[4];
        #pragma unroll
        for (int i = 0; i < 4; ++i)
            a[i] = *(const bf16x8*)&As[(wm + (i << 4) + l16) * 128 + swz];
        #pragma unroll
        for (int j = 0; j < 4; ++j)
            bv[j] = *(const bf16x8*)&Bs[(wn + (j << 4) + l16) * 128 + swz];
        #pragma unroll
        for (int i = 0; i < 4; ++i)
            #pragma unroll
            for (int j = 0; j < 4; ++j)
                acc[i][j] = __builtin_amdgcn_mfma_f32_16x16x32_bf16(
                    a[i], bv[j], acc[i][j], 0, 0, 0);
    }

    // Epilogue. D layout: col = lane&15 (tgt idx), row = q*4 + reg (src idx).
    const float* nrmS = ws + (size_t)b * NDIM + i0;
    const float* nrmT = ws + (size_t)BATCH * NDIM + (size_t)b * MDIM + j0;

    float sq[4][4], isq[4][4];
    #pragma unroll
    for (int i = 0; i < 4; ++i) {
        float4 s4v = *(const float4*)&nrmS[wm + (i << 4) + (q << 2)];
        sq[i][0] = s4v.x; sq[i][1] = s4v.y; sq[i][2] = s4v.z; sq[i][3] = s4v.w;
        #pragma unroll
        for (int r = 0; r < 4; ++r)
            isq[i][r] = __builtin_amdgcn_rsqf(fmaxf(sq[i][r], 1e-24f));
    }
    float tq[4], itq[4];
    #pragma unroll
    for (int j = 0; j < 4; ++j) {
        tq[j]  = nrmT[wn + (j << 4) + l16];
        itq[j] = __builtin_amdgcn_rsqf(fmaxf(tq[j], 1e-24f));
    }

    f32x2* out2 = (f32x2*)out;
    #pragma unroll
    for (int i = 0; i < 4; ++i) {
        #pragma unroll
        for (int r = 0; r < 4; ++r) {
            int mrow = wm + (i << 4) + (q << 2) + r;
            size_t rowbase = ((size_t)b * NDIM + (size_t)(i0 + mrow)) * MDIM + j0;
            float sqr = sq[i][r], isr = isq[i][r];
            #pragma unroll
            for (int j = 0; j < 4; ++j) {
                int ncol = wn + (j << 4) + l16;
                float d   = acc[i][j][r];
                float cs  = d * isr * itq[j];
                float dsq = fmaf(-2.0f, d, sqr + tq[j]);
                float fd  = __builtin_amdgcn_sqrtf(fmaxf(dsq, 0.0f));
                float fdn = __builtin_amdgcn_rcpf(1.0f + fd);
                f32x2 val = {cs, fdn};
                __builtin_nontemporal_store(val, &out2[rowbase + ncol]);
            }
        }
    }
}

extern "C" void kernel_launch(void* const* d_in, const int* in_sizes, int n_in,
                              void* d_out, int out_size, void* d_ws, size_t ws_size,
                              hipStream_t stream) {
    const float* src = (const float*)d_in[0];
    const float* tgt = (const float*)d_in[1];
    float* ws  = (float*)d_ws;
    float* out = (float*)d_out;

    // 16384 rows, one wave each -> 4096 blocks of 256.
    prep_kernel<<<dim3(4096), dim3(256), 0, stream>>>(src, tgt, ws);

    dim3 grid(MDIM / 128, NDIM / 128, BATCH);
    sim_mfma<<<grid, dim3(256), 0, stream>>>(ws, out);
}